// Round 6
// baseline (2825.244 us; speedup 1.0000x reference)
//
#include <hip/hip_runtime.h>

#define NB_PTS 4096   // points per cloud
#define MB_SEL 1024   // centroids per cloud
#define KNBR   64     // max neighbors
#define NCLOUD 4
#define NCENT  (NCLOUD * MB_SEL)   // 4096 centroids total

// exact np-order squared distance, f32: ((dx*dx + dy*dy) + dz*dz), no FMA
__device__ __forceinline__ float d2_np32(float dx, float dy, float dz) {
  return __fadd_rn(__fadd_rn(__fmul_rn(dx, dx), __fmul_rn(dy, dy)),
                   __fmul_rn(dz, dz));
}
// exact np-order squared distance, f64 (radius predicate — proven in round 5)
__device__ __forceinline__ double d2_np64(double dx, double dy, double dz) {
  return __dadd_rn(__dadd_rn(__dmul_rn(dx, dx), __dmul_rn(dy, dy)),
                   __dmul_rn(dz, dz));
}

// ---------------------------------------------------------------------------
// Kernel 1: farthest point sampling, exact np-float32 replication.
// One block (1024 thr) per cloud; single barrier per iteration via
// double-buffered partials + redundant per-wave final reduce.
// sel[k] stored as exact small floats in the batch_out region of d_out.
// ---------------------------------------------------------------------------
__global__ __launch_bounds__(1024) void fps_kernel(const float* __restrict__ pos,
                                                   float* __restrict__ selstash) {
  __shared__ float px[NB_PTS], py[NB_PTS], pz[NB_PTS];
  __shared__ float redv[2][16];
  __shared__ int   redi[2][16];
  const int b    = blockIdx.x;
  const int tid  = threadIdx.x;
  const int lane = tid & 63;
  const int wid  = tid >> 6;

  float mx[4], my[4], mz[4], dist[4];
#pragma unroll
  for (int q = 0; q < 4; ++q) {
    int j = tid + q * 1024;
    size_t base = ((size_t)b * NB_PTS + j) * 3;
    float X = pos[base], Y = pos[base + 1], Z = pos[base + 2];
    px[j] = X; py[j] = Y; pz[j] = Z;
    mx[q] = X; my[q] = Y; mz[q] = Z;
    dist[q] = __builtin_inff();
  }
  if (tid == 0) selstash[b * MB_SEL] = 0.0f;
  __syncthreads();

  int cur = 0;
  for (int k = 1; k < MB_SEL; ++k) {
    const float lx = px[cur], ly = py[cur], lz = pz[cur];
    float bestv = -__builtin_inff();
    int   besti = 0x7fffffff;
#pragma unroll
    for (int q = 0; q < 4; ++q) {
      float d2 = d2_np32(mx[q] - lx, my[q] - ly, mz[q] - lz);
      float d  = fminf(dist[q], d2);   // np.minimum, f32
      dist[q] = d;
      if (d > bestv) { bestv = d; besti = tid + q * 1024; }  // q asc -> lowest idx on tie
    }
#pragma unroll
    for (int off = 1; off < 64; off <<= 1) {
      float ov = __shfl_xor(bestv, off, 64);
      int   oi = __shfl_xor(besti, off, 64);
      if (ov > bestv || (ov == bestv && oi < besti)) { bestv = ov; besti = oi; }
    }
    const int buf = k & 1;
    if (lane == 0) { redv[buf][wid] = bestv; redi[buf][wid] = besti; }
    __syncthreads();
    // every wave redundantly reduces the 16 partials (no second barrier;
    // double-buffering makes the next iteration's writes race-free)
    float v  = (lane < 16) ? redv[buf][lane] : -__builtin_inff();
    int  idx = (lane < 16) ? redi[buf][lane] : 0x7fffffff;
#pragma unroll
    for (int off = 1; off < 16; off <<= 1) {
      float ov = __shfl_xor(v, off, 64);
      int   oi = __shfl_xor(idx, off, 64);
      if (ov > v || (ov == v && oi < idx)) { v = ov; idx = oi; }
    }
    int winner = __shfl(idx, 0, 64);
    if (tid == 0) selstash[b * MB_SEL + k] = (float)winner;
    cur = winner;
  }
}

// ---------------------------------------------------------------------------
// Kernel 2: fused radius (f64 predicate) + PointNetConv MLP (f32) + masked max.
// One 256-thr block per centroid; 2 passes of 32 neighbor rows (LDS ~34 KB ->
// 4 blocks/CU). Waves own disjoint output slices (4x less weight traffic).
// Per-output fmaf order identical to round 5 -> bitwise-same result.
// ---------------------------------------------------------------------------
template <int CIN, int INS>
__device__ __forceinline__ void layerW(const float* __restrict__ in,
                                       const float* __restrict__ W,
                                       const float* __restrict__ bias,
                                       float* __restrict__ out,
                                       int lane, int wv) {
  const int os = lane & 3;     // 8 outputs
  const int rg = lane >> 2;    // 2 rows
  const int o0 = wv * 32 + os * 8;
  float acc[2][8];
  {
    float4 c0 = *(const float4*)(bias + o0);
    float4 c4 = *(const float4*)(bias + o0 + 4);
    float bb[8] = {c0.x, c0.y, c0.z, c0.w, c4.x, c4.y, c4.z, c4.w};
#pragma unroll
    for (int r = 0; r < 2; ++r)
#pragma unroll
      for (int k = 0; k < 8; ++k) acc[r][k] = bb[k];
  }
  const float* in0 = in + (rg * 2) * INS;
#pragma unroll 4
  for (int i = 0; i < CIN; ++i) {
    float4 w0 = *(const float4*)(W + i * 128 + o0);
    float4 w4 = *(const float4*)(W + i * 128 + o0 + 4);
    float w[8] = {w0.x, w0.y, w0.z, w0.w, w4.x, w4.y, w4.z, w4.w};
#pragma unroll
    for (int r = 0; r < 2; ++r) {
      float f = in0[r * INS + i];
#pragma unroll
      for (int k = 0; k < 8; ++k) acc[r][k] = fmaf(f, w[k], acc[r][k]);
    }
  }
#pragma unroll
  for (int r = 0; r < 2; ++r) {
    float* orow = out + (rg * 2 + r) * 129 + o0;
#pragma unroll
    for (int k = 0; k < 8; ++k) orow[k] = fmaxf(acc[r][k], 0.f);
  }
}

__global__ __launch_bounds__(256, 4) void conv_kernel(
    const float* __restrict__ x, const float* __restrict__ pos,
    const float* __restrict__ W1, const float* __restrict__ b1,
    const float* __restrict__ W2, const float* __restrict__ b2,
    const float* __restrict__ W3, const float* __restrict__ b3,
    const float* __restrict__ selstash, float* __restrict__ out_x,
    float* __restrict__ out_pos, float* __restrict__ out_batch) {
  __shared__ float A[32 * 129];    // feat (stride 67, 2144 used) / h2 (stride 129)
  __shared__ float Bf[32 * 129];   // h1 (stride 129)
  __shared__ unsigned long long masks[64];
  __shared__ int nbrS[KNBR];
  __shared__ int nvS;

  const int tid  = threadIdx.x;
  const int lane = tid & 63;
  const int wv   = tid >> 6;
  const int c    = blockIdx.x;
  const int b    = c >> 10;
  const int s    = ((int)selstash[c]) & (NB_PTS - 1);
  const size_t qb = ((size_t)(b * NB_PTS + s)) * 3;
  const float qxf = pos[qb], qyf = pos[qb + 1], qzf = pos[qb + 2];
  const double qx = (double)qxf, qy = (double)qyf, qz = (double)qzf;
  const double RR = 0.2 * 0.2;

  // ---- radius phase: in-ball bitmask for all 4096 points (f64 predicate) ----
  for (int it = 0; it < 16; ++it) {
    const int ch = wv * 16 + it;
    const int j  = ch * 64 + lane;
    const size_t pb = ((size_t)b * NB_PTS + j) * 3;
    double d2 = d2_np64((double)pos[pb] - qx, (double)pos[pb + 1] - qy,
                        (double)pos[pb + 2] - qz);
    unsigned long long m = __ballot(d2 <= RR);
    if (lane == 0) masks[ch] = m;
  }
  __syncthreads();

  // ---- wave 0: ordered first-64 extraction via prefix popcount ----
  if (tid < 64) {
    unsigned long long m = masks[tid];
    int pc = __popcll(m);
    int incl = pc;
#pragma unroll
    for (int off = 1; off < 64; off <<= 1) {
      int o = __shfl_up(incl, off, 64);
      if (tid >= off) incl += o;
    }
    int base = incl - pc;
    int tot  = __shfl(incl, 63, 64);
    int nvw  = min(tot, KNBR);
    if (tid == 63) nvS = nvw;
    int slot = base;
    unsigned long long mm = m;
    while (mm && slot < KNBR) {
      int bit = __ffsll(mm) - 1;
      nbrS[slot++] = tid * 64 + bit;     // ascending global index order
      mm &= mm - 1;
    }
    if (tid >= nvw) nbrS[tid] = s;       // pad (masked out later)
  }
  __syncthreads();
  const int nv = nvS;

  // L3 lane mapping (persistent across passes)
  const int os3 = lane & 3;    // 16 outputs
  const int rg3 = lane >> 2;   // 2 rows
  const int o3  = wv * 64 + os3 * 16;
  float pm[16];
#pragma unroll
  for (int k = 0; k < 16; ++k) pm[k] = -1e9f;

  for (int pass = 0; pass < 2; ++pass) {
    // ---- gather 32 rows: feat = [x_j (64), pos_j - pos_i (3)], stride 67 ----
    {
      const int n = tid >> 3;      // row 0..31
      const int part = tid & 7;    // 8 x-feats each
      const int g = nbrS[pass * 32 + n];
      const float* xrow = x + (((size_t)(b * NB_PTS + g)) << 6);
      float4 u0 = *(const float4*)(xrow + part * 8);
      float4 u1 = *(const float4*)(xrow + part * 8 + 4);
      float* fr = A + n * 67 + part * 8;
      fr[0] = u0.x; fr[1] = u0.y; fr[2] = u0.z; fr[3] = u0.w;
      fr[4] = u1.x; fr[5] = u1.y; fr[6] = u1.z; fr[7] = u1.w;
      if (part == 0) {
        size_t gb = ((size_t)(b * NB_PTS + g)) * 3;
        float* fr2 = A + n * 67 + 64;
        fr2[0] = pos[gb]     - qxf;
        fr2[1] = pos[gb + 1] - qyf;
        fr2[2] = pos[gb + 2] - qzf;
      }
    }
    __syncthreads();
    layerW<67, 67>(A, W1, b1, Bf, lane, wv);     // feat -> h1
    __syncthreads();
    layerW<128, 129>(Bf, W2, b2, A, lane, wv);   // h1 -> h2
    __syncthreads();

    // ---- layer 3 (128 -> 256): wave-disjoint 64 outputs, 2 rows/lane ----
    {
      float acc[2][16];
      {
        float bb[16];
#pragma unroll
        for (int t = 0; t < 4; ++t) {
          float4 u = *(const float4*)(b3 + o3 + t * 4);
          bb[t*4] = u.x; bb[t*4+1] = u.y; bb[t*4+2] = u.z; bb[t*4+3] = u.w;
        }
#pragma unroll
        for (int r = 0; r < 2; ++r)
#pragma unroll
          for (int k = 0; k < 16; ++k) acc[r][k] = bb[k];
      }
      const float* in0 = A + (rg3 * 2) * 129;
#pragma unroll 2
      for (int i = 0; i < 128; ++i) {
        float w[16];
#pragma unroll
        for (int t = 0; t < 4; ++t) {
          float4 u = *(const float4*)(W3 + i * 256 + o3 + t * 4);
          w[t*4] = u.x; w[t*4+1] = u.y; w[t*4+2] = u.z; w[t*4+3] = u.w;
        }
#pragma unroll
        for (int r = 0; r < 2; ++r) {
          float f = in0[r * 129 + i];
#pragma unroll
          for (int k = 0; k < 16; ++k) acc[r][k] = fmaf(f, w[k], acc[r][k]);
        }
      }
#pragma unroll
      for (int r = 0; r < 2; ++r) {
        const bool val = (pass * 32 + rg3 * 2 + r) < nv;
#pragma unroll
        for (int k = 0; k < 16; ++k) {
          float h = fmaxf(acc[r][k], 0.f);
          pm[k] = fmaxf(pm[k], val ? h : -1e9f);
        }
      }
    }
    __syncthreads();   // A (h2) consumed; next pass's gather may overwrite
  }

  // ---- epilogue: butterfly max over the 16 rg groups, direct global write ----
#pragma unroll
  for (int off = 4; off < 64; off <<= 1) {
#pragma unroll
    for (int k = 0; k < 16; ++k) pm[k] = fmaxf(pm[k], __shfl_xor(pm[k], off, 64));
  }
  if (rg3 == 0) {   // lanes 0..3 of each wave hold the final 16 outs each
    float* orow = out_x + (size_t)c * 256 + o3;
#pragma unroll
    for (int k = 0; k < 16; k += 4) {
      *(float4*)(orow + k) = make_float4(pm[k], pm[k+1], pm[k+2], pm[k+3]);
    }
  }
  if (tid < 3) out_pos[c * 3 + tid] = pos[qb + tid];
  if (tid == 0) out_batch[c] = (float)b;   // overwrite sel stash
}

extern "C" void kernel_launch(void* const* d_in, const int* in_sizes, int n_in,
                              void* d_out, int out_size, void* d_ws, size_t ws_size,
                              hipStream_t stream) {
  const float* x   = (const float*)d_in[0];
  const float* pos = (const float*)d_in[1];
  // d_in[2] = batch (int32) — layout known (arange(N)//NB), unused
  const float* W1 = (const float*)d_in[3];
  const float* b1 = (const float*)d_in[4];
  const float* W2 = (const float*)d_in[5];
  const float* b2 = (const float*)d_in[6];
  const float* W3 = (const float*)d_in[7];
  const float* b3 = (const float*)d_in[8];

  float* out = (float*)d_out;
  float* out_pos   = out + (size_t)NCENT * 256;     // after x_out
  float* out_batch = out_pos + (size_t)NCENT * 3;   // after pos_out

  fps_kernel<<<NCLOUD, 1024, 0, stream>>>(pos, out_batch);
  conv_kernel<<<NCENT, 256, 0, stream>>>(x, pos, W1, b1, W2, b2, W3, b3,
                                         out_batch, out, out_pos, out_batch);
}

// Round 7
// 1744.011 us; speedup vs baseline: 1.6200x; 1.6200x over previous
//
#include <hip/hip_runtime.h>

#define NB_PTS 4096   // points per cloud
#define MB_SEL 1024   // centroids per cloud
#define KNBR   64     // max neighbors
#define NCLOUD 4
#define NCENT  (NCLOUD * MB_SEL)   // 4096 centroids total

// exact np-order squared distance, f32: ((dx*dx + dy*dy) + dz*dz), no FMA
__device__ __forceinline__ float d2_np32(float dx, float dy, float dz) {
  return __fadd_rn(__fadd_rn(__fmul_rn(dx, dx), __fmul_rn(dy, dy)),
                   __fmul_rn(dz, dz));
}
// exact np-order squared distance, f64 (radius predicate — proven round 5/6)
__device__ __forceinline__ double d2_np64(double dx, double dy, double dz) {
  return __dadd_rn(__dadd_rn(__dmul_rn(dx, dx), __dmul_rn(dy, dy)),
                   __dmul_rn(dz, dz));
}

// ---------------------------------------------------------------------------
// Kernel 1: farthest point sampling, exact np-float32 replication.
// 256 threads (4 waves = 1 wave/SIMD, no issue contention), 16 points/thread.
// Single barrier/iter via double-buffered 4-slot partials.
// ---------------------------------------------------------------------------
__global__ __launch_bounds__(256) void fps_kernel(const float* __restrict__ pos,
                                                  float* __restrict__ selstash) {
  __shared__ float px[NB_PTS], py[NB_PTS], pz[NB_PTS];
  __shared__ float redv[2][4];
  __shared__ int   redi[2][4];
  const int b    = blockIdx.x;
  const int tid  = threadIdx.x;
  const int lane = tid & 63;
  const int wv   = tid >> 6;

  float mx[16], my[16], mz[16], dist[16];
#pragma unroll
  for (int q = 0; q < 16; ++q) {
    int j = tid + q * 256;
    size_t base = ((size_t)b * NB_PTS + j) * 3;
    float X = pos[base], Y = pos[base + 1], Z = pos[base + 2];
    px[j] = X; py[j] = Y; pz[j] = Z;
    mx[q] = X; my[q] = Y; mz[q] = Z;
    dist[q] = __builtin_inff();
  }
  if (tid == 0) selstash[b * MB_SEL] = 0.0f;
  __syncthreads();

  int cur = 0;
  for (int k = 1; k < MB_SEL; ++k) {
    const float lx = px[cur], ly = py[cur], lz = pz[cur];
    float bestv = -__builtin_inff();
    int   besti = 0x7fffffff;
#pragma unroll
    for (int q = 0; q < 16; ++q) {
      float d2 = d2_np32(mx[q] - lx, my[q] - ly, mz[q] - lz);
      float d  = fminf(dist[q], d2);   // np.minimum, f32
      dist[q] = d;
      bool gt = d > bestv;             // q asc -> lowest idx kept on ties
      bestv = gt ? d : bestv;
      besti = gt ? (tid + q * 256) : besti;
    }
#pragma unroll
    for (int off = 1; off < 64; off <<= 1) {
      float ov = __shfl_xor(bestv, off, 64);
      int   oi = __shfl_xor(besti, off, 64);
      if (ov > bestv || (ov == bestv && oi < besti)) { bestv = ov; besti = oi; }
    }
    const int buf = k & 1;
    if (lane == 0) { redv[buf][wv] = bestv; redi[buf][wv] = besti; }
    __syncthreads();
    float v  = (lane < 4) ? redv[buf][lane] : -__builtin_inff();
    int  idx = (lane < 4) ? redi[buf][lane] : 0x7fffffff;
#pragma unroll
    for (int off = 1; off < 4; off <<= 1) {
      float ov = __shfl_xor(v, off, 64);
      int   oi = __shfl_xor(idx, off, 64);
      if (ov > v || (ov == v && oi < idx)) { v = ov; idx = oi; }
    }
    int winner = __shfl(idx, 0, 64);
    if (tid == 0) selstash[b * MB_SEL + k] = (float)winner;
    cur = winner;
  }
}

// ---------------------------------------------------------------------------
// Kernel 2: fused radius (f64) + MLP (f32) + masked max. One 256-thr block per
// centroid; 2 passes x 32 rows (LDS ~33 KB -> 4 blocks/CU). Thread tiles:
// L1/L2 4 rows x 4 outs, L3 4 rows x 8 outs; i-loop vectorized by 4.
// Per-output fmaf order identical to rounds 5/6 -> bitwise-same output.
// ---------------------------------------------------------------------------
__global__ __launch_bounds__(256, 4) void conv_kernel(
    const float* __restrict__ x, const float* __restrict__ pos,
    const float* __restrict__ W1, const float* __restrict__ b1,
    const float* __restrict__ W2, const float* __restrict__ b2,
    const float* __restrict__ W3, const float* __restrict__ b3,
    const float* __restrict__ selstash, float* __restrict__ out_x,
    float* __restrict__ out_pos, float* __restrict__ out_batch) {
  __shared__ float A[32 * 128];    // feat (stride 68) / h2 (stride 128)
  __shared__ float Bf[32 * 128];   // h1 (stride 128) / epilogue partials [8][256]
  __shared__ unsigned long long masks[64];
  __shared__ int nbrS[KNBR];
  __shared__ int nvS;

  const int tid  = threadIdx.x;
  const int lane = tid & 63;
  const int wv   = tid >> 6;
  const int c    = blockIdx.x;
  const int b    = c >> 10;
  const int s    = ((int)selstash[c]) & (NB_PTS - 1);
  const size_t qb = ((size_t)(b * NB_PTS + s)) * 3;
  const float qxf = pos[qb], qyf = pos[qb + 1], qzf = pos[qb + 2];
  const double qx = (double)qxf, qy = (double)qyf, qz = (double)qzf;
  const double RR = 0.2 * 0.2;

  // ---- radius phase: in-ball bitmask for all 4096 points (f64 predicate) ----
  for (int it = 0; it < 16; ++it) {
    const int ch = wv * 16 + it;
    const int j  = ch * 64 + lane;
    const size_t pb = ((size_t)b * NB_PTS + j) * 3;
    double d2 = d2_np64((double)pos[pb] - qx, (double)pos[pb + 1] - qy,
                        (double)pos[pb + 2] - qz);
    unsigned long long m = __ballot(d2 <= RR);
    if (lane == 0) masks[ch] = m;
  }
  __syncthreads();

  // ---- wave 0: ordered first-64 extraction via prefix popcount ----
  if (tid < 64) {
    unsigned long long m = masks[tid];
    int pc = __popcll(m);
    int incl = pc;
#pragma unroll
    for (int off = 1; off < 64; off <<= 1) {
      int o = __shfl_up(incl, off, 64);
      if (tid >= off) incl += o;
    }
    int base = incl - pc;
    int tot  = __shfl(incl, 63, 64);
    int nvw  = min(tot, KNBR);
    if (tid == 63) nvS = nvw;
    int slot = base;
    unsigned long long mm = m;
    while (mm && slot < KNBR) {
      int bit = __ffsll(mm) - 1;
      nbrS[slot++] = tid * 64 + bit;     // ascending global index order
      mm &= mm - 1;
    }
    if (tid >= nvw) nbrS[tid] = s;       // pad (masked out later)
  }
  __syncthreads();
  const int nv = nvS;

  const int og = tid & 31;   // L1/L2: 4 outs at og*4 ; L3: 8 outs at og*8
  const int rg = tid >> 5;   // 8 row-groups x 4 rows
  const int r0 = rg * 4;
  float pm[8];
#pragma unroll
  for (int k = 0; k < 8; ++k) pm[k] = -1e9f;

  for (int pass = 0; pass < 2; ++pass) {
    // ---- gather 32 rows: feat = [x_j (64), pos_j - pos_i (3)], stride 68 ----
    {
      const int n = tid >> 3;      // row 0..31
      const int part = tid & 7;    // 8 x-feats each
      const int g = nbrS[pass * 32 + n];
      const float* xrow = x + (((size_t)(b * NB_PTS + g)) << 6);
      float4 u0 = *(const float4*)(xrow + part * 8);
      float4 u1 = *(const float4*)(xrow + part * 8 + 4);
      float* fr = A + n * 68 + part * 8;
      *(float4*)fr = u0;
      *(float4*)(fr + 4) = u1;
      if (part == 0) {
        size_t gb = ((size_t)(b * NB_PTS + g)) * 3;
        float* fr2 = A + n * 68 + 64;
        fr2[0] = pos[gb]     - qxf;
        fr2[1] = pos[gb + 1] - qyf;
        fr2[2] = pos[gb + 2] - qzf;
      }
    }
    __syncthreads();

    // ---- L1: 67 -> 128 (feat in A str68 -> h1 in Bf str128) ----
    {
      const int o0 = og * 4;
      float acc[4][4];
      {
        float4 bb = *(const float4*)(b1 + o0);
#pragma unroll
        for (int r = 0; r < 4; ++r) {
          acc[r][0] = bb.x; acc[r][1] = bb.y; acc[r][2] = bb.z; acc[r][3] = bb.w;
        }
      }
#pragma unroll 4
      for (int i = 0; i < 64; i += 4) {
        float4 w0 = *(const float4*)(W1 + (i + 0) * 128 + o0);
        float4 w1 = *(const float4*)(W1 + (i + 1) * 128 + o0);
        float4 w2 = *(const float4*)(W1 + (i + 2) * 128 + o0);
        float4 w3 = *(const float4*)(W1 + (i + 3) * 128 + o0);
        float4 f[4];
#pragma unroll
        for (int r = 0; r < 4; ++r) f[r] = *(const float4*)(A + (r0 + r) * 68 + i);
#pragma unroll
        for (int r = 0; r < 4; ++r) {
          acc[r][0] = fmaf(f[r].x, w0.x, acc[r][0]); acc[r][1] = fmaf(f[r].x, w0.y, acc[r][1]);
          acc[r][2] = fmaf(f[r].x, w0.z, acc[r][2]); acc[r][3] = fmaf(f[r].x, w0.w, acc[r][3]);
          acc[r][0] = fmaf(f[r].y, w1.x, acc[r][0]); acc[r][1] = fmaf(f[r].y, w1.y, acc[r][1]);
          acc[r][2] = fmaf(f[r].y, w1.z, acc[r][2]); acc[r][3] = fmaf(f[r].y, w1.w, acc[r][3]);
          acc[r][0] = fmaf(f[r].z, w2.x, acc[r][0]); acc[r][1] = fmaf(f[r].z, w2.y, acc[r][1]);
          acc[r][2] = fmaf(f[r].z, w2.z, acc[r][2]); acc[r][3] = fmaf(f[r].z, w2.w, acc[r][3]);
          acc[r][0] = fmaf(f[r].w, w3.x, acc[r][0]); acc[r][1] = fmaf(f[r].w, w3.y, acc[r][1]);
          acc[r][2] = fmaf(f[r].w, w3.z, acc[r][2]); acc[r][3] = fmaf(f[r].w, w3.w, acc[r][3]);
        }
      }
      for (int i = 64; i < 67; ++i) {    // tail
        float4 w0 = *(const float4*)(W1 + i * 128 + o0);
#pragma unroll
        for (int r = 0; r < 4; ++r) {
          float fv = A[(r0 + r) * 68 + i];
          acc[r][0] = fmaf(fv, w0.x, acc[r][0]); acc[r][1] = fmaf(fv, w0.y, acc[r][1]);
          acc[r][2] = fmaf(fv, w0.z, acc[r][2]); acc[r][3] = fmaf(fv, w0.w, acc[r][3]);
        }
      }
#pragma unroll
      for (int r = 0; r < 4; ++r) {
        *(float4*)(Bf + (r0 + r) * 128 + o0) =
            make_float4(fmaxf(acc[r][0], 0.f), fmaxf(acc[r][1], 0.f),
                        fmaxf(acc[r][2], 0.f), fmaxf(acc[r][3], 0.f));
      }
    }
    __syncthreads();

    // ---- L2: 128 -> 128 (h1 in Bf str128 -> h2 in A str128) ----
    {
      const int o0 = og * 4;
      float acc[4][4];
      {
        float4 bb = *(const float4*)(b2 + o0);
#pragma unroll
        for (int r = 0; r < 4; ++r) {
          acc[r][0] = bb.x; acc[r][1] = bb.y; acc[r][2] = bb.z; acc[r][3] = bb.w;
        }
      }
#pragma unroll 4
      for (int i = 0; i < 128; i += 4) {
        float4 w0 = *(const float4*)(W2 + (i + 0) * 128 + o0);
        float4 w1 = *(const float4*)(W2 + (i + 1) * 128 + o0);
        float4 w2 = *(const float4*)(W2 + (i + 2) * 128 + o0);
        float4 w3 = *(const float4*)(W2 + (i + 3) * 128 + o0);
        float4 f[4];
#pragma unroll
        for (int r = 0; r < 4; ++r) f[r] = *(const float4*)(Bf + (r0 + r) * 128 + i);
#pragma unroll
        for (int r = 0; r < 4; ++r) {
          acc[r][0] = fmaf(f[r].x, w0.x, acc[r][0]); acc[r][1] = fmaf(f[r].x, w0.y, acc[r][1]);
          acc[r][2] = fmaf(f[r].x, w0.z, acc[r][2]); acc[r][3] = fmaf(f[r].x, w0.w, acc[r][3]);
          acc[r][0] = fmaf(f[r].y, w1.x, acc[r][0]); acc[r][1] = fmaf(f[r].y, w1.y, acc[r][1]);
          acc[r][2] = fmaf(f[r].y, w1.z, acc[r][2]); acc[r][3] = fmaf(f[r].y, w1.w, acc[r][3]);
          acc[r][0] = fmaf(f[r].z, w2.x, acc[r][0]); acc[r][1] = fmaf(f[r].z, w2.y, acc[r][1]);
          acc[r][2] = fmaf(f[r].z, w2.z, acc[r][2]); acc[r][3] = fmaf(f[r].z, w2.w, acc[r][3]);
          acc[r][0] = fmaf(f[r].w, w3.x, acc[r][0]); acc[r][1] = fmaf(f[r].w, w3.y, acc[r][1]);
          acc[r][2] = fmaf(f[r].w, w3.z, acc[r][2]); acc[r][3] = fmaf(f[r].w, w3.w, acc[r][3]);
        }
      }
#pragma unroll
      for (int r = 0; r < 4; ++r) {
        *(float4*)(A + (r0 + r) * 128 + o0) =
            make_float4(fmaxf(acc[r][0], 0.f), fmaxf(acc[r][1], 0.f),
                        fmaxf(acc[r][2], 0.f), fmaxf(acc[r][3], 0.f));
      }
    }
    __syncthreads();

    // ---- L3: 128 -> 256 (h2 in A str128), 4 rows x 8 outs, fold masked max ----
    {
      const int o0 = og * 8;
      float acc[4][8];
      {
        float4 c0 = *(const float4*)(b3 + o0);
        float4 c4 = *(const float4*)(b3 + o0 + 4);
#pragma unroll
        for (int r = 0; r < 4; ++r) {
          acc[r][0] = c0.x; acc[r][1] = c0.y; acc[r][2] = c0.z; acc[r][3] = c0.w;
          acc[r][4] = c4.x; acc[r][5] = c4.y; acc[r][6] = c4.z; acc[r][7] = c4.w;
        }
      }
#pragma unroll 2
      for (int i = 0; i < 128; i += 4) {
        float4 f[4];
#pragma unroll
        for (int r = 0; r < 4; ++r) f[r] = *(const float4*)(A + (r0 + r) * 128 + i);
#pragma unroll
        for (int j = 0; j < 4; ++j) {
          float4 wa = *(const float4*)(W3 + (i + j) * 256 + o0);
          float4 wb = *(const float4*)(W3 + (i + j) * 256 + o0 + 4);
          float w[8] = {wa.x, wa.y, wa.z, wa.w, wb.x, wb.y, wb.z, wb.w};
#pragma unroll
          for (int r = 0; r < 4; ++r) {
            float fv = (j == 0) ? f[r].x : (j == 1) ? f[r].y : (j == 2) ? f[r].z : f[r].w;
#pragma unroll
            for (int k = 0; k < 8; ++k) acc[r][k] = fmaf(fv, w[k], acc[r][k]);
          }
        }
      }
#pragma unroll
      for (int r = 0; r < 4; ++r) {
        const bool val = (pass * 32 + r0 + r) < nv;
#pragma unroll
        for (int k = 0; k < 8; ++k) {
          float h = fmaxf(acc[r][k], 0.f);
          pm[k] = fmaxf(pm[k], val ? h : -1e9f);
        }
      }
    }
    __syncthreads();   // A (h2) consumed; next pass's gather may overwrite
  }

  // ---- epilogue: write 8 partials/thread, reduce 8 row-groups per output ----
  {
    float* pr = Bf + rg * 256 + og * 8;   // Bf reused: [8][256]
    *(float4*)pr = make_float4(pm[0], pm[1], pm[2], pm[3]);
    *(float4*)(pr + 4) = make_float4(pm[4], pm[5], pm[6], pm[7]);
  }
  __syncthreads();
  {
    float v = Bf[tid];
#pragma unroll
    for (int g = 1; g < 8; ++g) v = fmaxf(v, Bf[g * 256 + tid]);
    out_x[(size_t)c * 256 + tid] = v;
  }
  if (tid < 3) out_pos[c * 3 + tid] = pos[qb + tid];
  if (tid == 0) out_batch[c] = (float)b;   // overwrite sel stash
}

extern "C" void kernel_launch(void* const* d_in, const int* in_sizes, int n_in,
                              void* d_out, int out_size, void* d_ws, size_t ws_size,
                              hipStream_t stream) {
  const float* x   = (const float*)d_in[0];
  const float* pos = (const float*)d_in[1];
  // d_in[2] = batch (int32) — layout known (arange(N)//NB), unused
  const float* W1 = (const float*)d_in[3];
  const float* b1 = (const float*)d_in[4];
  const float* W2 = (const float*)d_in[5];
  const float* b2 = (const float*)d_in[6];
  const float* W3 = (const float*)d_in[7];
  const float* b3 = (const float*)d_in[8];

  float* out = (float*)d_out;
  float* out_pos   = out + (size_t)NCENT * 256;     // after x_out
  float* out_batch = out_pos + (size_t)NCENT * 3;   // after pos_out

  fps_kernel<<<NCLOUD, 256, 0, stream>>>(pos, out_batch);
  conv_kernel<<<NCENT, 256, 0, stream>>>(x, pos, W1, b1, W2, b2, W3, b3,
                                         out_batch, out, out_pos, out_batch);
}

// Round 8
// 982.099 us; speedup vs baseline: 2.8767x; 1.7758x over previous
//
#include <hip/hip_runtime.h>

typedef unsigned int UI;
typedef unsigned long long ULL;
typedef _Float16 f16;
typedef _Float16 h8 __attribute__((ext_vector_type(8)));
typedef float f32x4 __attribute__((ext_vector_type(4)));

#define NB_PTS 4096
#define MB_SEL 1024
#define KNBR   64
#define NCLOUD 4
#define NCENT  (NCLOUD * MB_SEL)

// ws layout (f16): Wt1[128][96] @0 ; Wt2[128][128] @12288 ; Wt3[256][128] @28672
#define WT2_OFF 12288
#define WT3_OFF 28672
#define WS_ELEMS 61440

// exact np-order squared distance, f32
__device__ __forceinline__ float d2_np32(float dx, float dy, float dz) {
  return __fadd_rn(__fadd_rn(__fmul_rn(dx, dx), __fmul_rn(dy, dy)),
                   __fmul_rn(dz, dz));
}
// exact np-order squared distance, f64 (radius predicate — proven)
__device__ __forceinline__ double d2_np64(double dx, double dy, double dz) {
  return __dadd_rn(__dadd_rn(__dmul_rn(dx, dx), __dmul_rn(dy, dy)),
                   __dmul_rn(dz, dz));
}

// ---------------------------------------------------------------------------
// Kernel 0: weight prep — f32 -> f16, transposed to [n][k], K of W1 padded to 96
// ---------------------------------------------------------------------------
__global__ __launch_bounds__(256) void prep_kernel(const float* __restrict__ W1,
                                                   const float* __restrict__ W2,
                                                   const float* __restrict__ W3,
                                                   f16* __restrict__ ws) {
  int t = blockIdx.x * 256 + threadIdx.x;
  if (t < WT2_OFF) {                       // Wt1[n][k] : 128 x 96
    int n = t / 96, k = t - n * 96;
    ws[t] = (k < 67) ? (f16)W1[k * 128 + n] : (f16)0.f;
  } else if (t < WT3_OFF) {                // Wt2[n][k] : 128 x 128
    int u = t - WT2_OFF;
    int n = u >> 7, k = u & 127;
    ws[t] = (f16)W2[k * 128 + n];
  } else {                                 // Wt3[n][k] : 256 x 128
    int u = t - WT3_OFF;
    int n = u >> 7, k = u & 127;
    ws[t] = (f16)W3[k * 256 + n];
  }
}

// ---------------------------------------------------------------------------
// Kernel 1: FPS, exact np-float32 replication. 256 thr x 16 pts.
// Reduction via packed u64 keys (d_bits<<32 | ~idx) + per-wave LDS atomicMax;
// 3-phase slot rotation, ONE barrier per iter, zero shuffles.
// ---------------------------------------------------------------------------
__global__ __launch_bounds__(256) void fps_kernel(const float* __restrict__ pos,
                                                  float* __restrict__ selstash) {
  __shared__ float px[NB_PTS], py[NB_PTS], pz[NB_PTS];
  __shared__ ULL slots[3][4];
  const int b    = blockIdx.x;
  const int tid  = threadIdx.x;
  const int lane = tid & 63;
  const int wv   = tid >> 6;

  float mx[16], my[16], mz[16], dist[16];
#pragma unroll
  for (int q = 0; q < 16; ++q) {
    int j = tid + q * 256;
    size_t base = ((size_t)b * NB_PTS + j) * 3;
    float X = pos[base], Y = pos[base + 1], Z = pos[base + 2];
    px[j] = X; py[j] = Y; pz[j] = Z;
    mx[q] = X; my[q] = Y; mz[q] = Z;
    dist[q] = __builtin_inff();
  }
  if (tid < 12) ((ULL*)slots)[tid] = 0ull;
  if (tid == 0) selstash[b * MB_SEL] = 0.0f;
  __syncthreads();

  float lx = px[0], ly = py[0], lz = pz[0];
  for (int k = 1; k < MB_SEL; ++k) {
    float bestv = -__builtin_inff();
    int   besti = 0x7fffffff;
#pragma unroll
    for (int q = 0; q < 16; ++q) {
      float d2 = d2_np32(mx[q] - lx, my[q] - ly, mz[q] - lz);
      float d  = fminf(dist[q], d2);     // np.minimum, f32
      dist[q] = d;
      bool gt = d > bestv;               // strict > keeps lowest q on tie
      bestv = gt ? d : bestv;
      besti = gt ? (tid + q * 256) : besti;
    }
    // key: larger d wins; on tie, smaller idx wins (np.argmax first-max)
    ULL key = ((ULL)__float_as_uint(bestv) << 32) | (ULL)(~(UI)besti);
    const int buf = k % 3;
    atomicMax(&slots[buf][wv], key);
    if (lane == 0) slots[(k + 1) % 3][wv] = 0ull;   // reset for next iter
    __syncthreads();
    ULL s0 = slots[buf][0], s1 = slots[buf][1];
    ULL s2 = slots[buf][2], s3 = slots[buf][3];
    ULL m01 = s0 > s1 ? s0 : s1;
    ULL m23 = s2 > s3 ? s2 : s3;
    ULL mk  = m01 > m23 ? m01 : m23;
    int winner = (int)(~(UI)mk);
    if (tid == 0) selstash[b * MB_SEL + k] = (float)winner;
    lx = px[winner]; ly = py[winner]; lz = pz[winner];
  }
}

// ---------------------------------------------------------------------------
// Kernel 2: fused radius (f64) + MFMA-f16 MLP + masked max.
// One 256-thr block per centroid. Wave w owns neighbor rows 16w..16w+15 for the
// whole MLP (wave-private h tiles -> no inter-layer barriers).
// MFMA layouts (verified, learn_hip m89/m91/m97):
//   A[m=lane&15][k=quad*8+j], B[n=lane&15][k=quad*8+j], D col=lane&15 row=quad*4+reg
// ---------------------------------------------------------------------------
__global__ __launch_bounds__(256, 3) void conv_kernel(
    const float* __restrict__ x, const float* __restrict__ pos,
    const float* __restrict__ b1, const float* __restrict__ b2,
    const float* __restrict__ b3, const f16* __restrict__ ws,
    const float* __restrict__ selstash, float* __restrict__ out_x,
    float* __restrict__ out_pos, float* __restrict__ out_batch) {
  __shared__ f16 featA[64 * 104];   // [row][k<96], stride 104
  __shared__ f16 h1s[64 * 136];     // [row][k<128], stride 136
  __shared__ f16 h2s[64 * 136];
  __shared__ float pmax[4 * 256];
  __shared__ ULL masks[64];
  __shared__ int nbrS[KNBR];
  __shared__ int nvS;

  const int tid  = threadIdx.x;
  const int lane = tid & 63;
  const int wv   = tid >> 6;
  const int c    = blockIdx.x;
  const int b    = c >> 10;
  const int s    = ((int)selstash[c]) & (NB_PTS - 1);
  const size_t qb = ((size_t)(b * NB_PTS + s)) * 3;
  const float qxf = pos[qb], qyf = pos[qb + 1], qzf = pos[qb + 2];
  const double qx = (double)qxf, qy = (double)qyf, qz = (double)qzf;
  const double RR = 0.2 * 0.2;

  // ---- radius: in-ball bitmask over all 4096 points ----
  for (int it = 0; it < 16; ++it) {
    const int ch = wv * 16 + it;
    const int j  = ch * 64 + lane;
    const size_t pb = ((size_t)b * NB_PTS + j) * 3;
    double d2 = d2_np64((double)pos[pb] - qx, (double)pos[pb + 1] - qy,
                        (double)pos[pb + 2] - qz);
    ULL m = __ballot(d2 <= RR);
    if (lane == 0) masks[ch] = m;
  }
  __syncthreads();

  // ---- wave 0: first-64 in-ball extraction (ascending index) ----
  if (tid < 64) {
    ULL m = masks[tid];
    int pc = __popcll(m);
    int incl = pc;
#pragma unroll
    for (int off = 1; off < 64; off <<= 1) {
      int o = __shfl_up(incl, off, 64);
      if (tid >= off) incl += o;
    }
    int base = incl - pc;
    int tot  = __shfl(incl, 63, 64);
    int nvw  = min(tot, KNBR);
    if (tid == 63) nvS = nvw;
    int slot = base;
    ULL mm = m;
    while (mm && slot < KNBR) {
      int bit = __ffsll(mm) - 1;
      nbrS[slot++] = tid * 64 + bit;
      mm &= mm - 1;
    }
    if (tid >= nvw) nbrS[tid] = s;
  }
  __syncthreads();
  const int nv = nvS;

  // ---- gather (wave-private rows): feat=[x_j, pos_j-pos_i, 0-pad], f16 ----
  {
    const int r = 16 * wv + (lane >> 2);   // this wave's rows
    const int part = lane & 3;             // 16 x-feats each
    const int g = nbrS[r];
    const float* xrow = x + (((size_t)(b * NB_PTS + g)) << 6) + part * 16;
    float4 u0 = *(const float4*)(xrow);
    float4 u1 = *(const float4*)(xrow + 4);
    float4 u2 = *(const float4*)(xrow + 8);
    float4 u3 = *(const float4*)(xrow + 12);
    h8 o0, o1;
    o0[0]=(f16)u0.x; o0[1]=(f16)u0.y; o0[2]=(f16)u0.z; o0[3]=(f16)u0.w;
    o0[4]=(f16)u1.x; o0[5]=(f16)u1.y; o0[6]=(f16)u1.z; o0[7]=(f16)u1.w;
    o1[0]=(f16)u2.x; o1[1]=(f16)u2.y; o1[2]=(f16)u2.z; o1[3]=(f16)u2.w;
    o1[4]=(f16)u3.x; o1[5]=(f16)u3.y; o1[6]=(f16)u3.z; o1[7]=(f16)u3.w;
    *(h8*)(featA + r * 104 + part * 16)     = o0;
    *(h8*)(featA + r * 104 + part * 16 + 8) = o1;
    if (part == 3) {
      size_t gb = ((size_t)(b * NB_PTS + g)) * 3;
      h8 rv = {(f16)0.f,(f16)0.f,(f16)0.f,(f16)0.f,(f16)0.f,(f16)0.f,(f16)0.f,(f16)0.f};
      rv[0] = (f16)(pos[gb]     - qxf);
      rv[1] = (f16)(pos[gb + 1] - qyf);
      rv[2] = (f16)(pos[gb + 2] - qzf);
      h8 z = {(f16)0.f,(f16)0.f,(f16)0.f,(f16)0.f,(f16)0.f,(f16)0.f,(f16)0.f,(f16)0.f};
      *(h8*)(featA + r * 104 + 64) = rv;
      *(h8*)(featA + r * 104 + 72) = z;
      *(h8*)(featA + r * 104 + 80) = z;
      *(h8*)(featA + r * 104 + 88) = z;
    }
  }
  // wave-private from here: no barrier until epilogue

  const int n    = lane & 15;
  const int quad = lane >> 4;
  const f16* Wt1 = ws;
  const f16* Wt2 = ws + WT2_OFF;
  const f16* Wt3 = ws + WT3_OFF;
  const int rowA = (16 * wv + n) * 104;   // A-frag row base (featA)
  const int rowH = (16 * wv + n) * 136;   // A-frag row base (h LDS)
  const int rw   = 16 * wv + quad * 4;    // D rows this lane writes

  // ---- L1: 67(->96) -> 128 ----
#pragma unroll
  for (int ct = 0; ct < 8; ++ct) {
    f32x4 acc = {0.f, 0.f, 0.f, 0.f};
#pragma unroll
    for (int kt = 0; kt < 3; ++kt) {
      h8 a = *(const h8*)(featA + rowA + kt * 32 + quad * 8);
      h8 w = *(const h8*)(Wt1 + (ct * 16 + n) * 96 + kt * 32 + quad * 8);
      acc = __builtin_amdgcn_mfma_f32_16x16x32_f16(a, w, acc, 0, 0, 0);
    }
    float bs = b1[ct * 16 + n];
#pragma unroll
    for (int r = 0; r < 4; ++r)
      h1s[(rw + r) * 136 + ct * 16 + n] = (f16)fmaxf(acc[r] + bs, 0.f);
  }
  // ---- L2: 128 -> 128 ----
#pragma unroll
  for (int ct = 0; ct < 8; ++ct) {
    f32x4 acc = {0.f, 0.f, 0.f, 0.f};
#pragma unroll
    for (int kt = 0; kt < 4; ++kt) {
      h8 a = *(const h8*)(h1s + rowH + kt * 32 + quad * 8);
      h8 w = *(const h8*)(Wt2 + (ct * 16 + n) * 128 + kt * 32 + quad * 8);
      acc = __builtin_amdgcn_mfma_f32_16x16x32_f16(a, w, acc, 0, 0, 0);
    }
    float bs = b2[ct * 16 + n];
#pragma unroll
    for (int r = 0; r < 4; ++r)
      h2s[(rw + r) * 136 + ct * 16 + n] = (f16)fmaxf(acc[r] + bs, 0.f);
  }
  // ---- L3: 128 -> 256, fused bias+relu+validity+row-max ----
#pragma unroll
  for (int ct = 0; ct < 16; ++ct) {
    f32x4 acc = {0.f, 0.f, 0.f, 0.f};
#pragma unroll
    for (int kt = 0; kt < 4; ++kt) {
      h8 a = *(const h8*)(h2s + rowH + kt * 32 + quad * 8);
      h8 w = *(const h8*)(Wt3 + (ct * 16 + n) * 128 + kt * 32 + quad * 8);
      acc = __builtin_amdgcn_mfma_f32_16x16x32_f16(a, w, acc, 0, 0, 0);
    }
    float bs = b3[ct * 16 + n];
    float vmax = 0.f;   // valid max >= 0 (relu, nv>=1) -> 0-mask == -1e9-mask
#pragma unroll
    for (int r = 0; r < 4; ++r) {
      float h = fmaxf(acc[r] + bs, 0.f);
      vmax = fmaxf(vmax, (rw + r) < nv ? h : 0.f);
    }
    vmax = fmaxf(vmax, __shfl_xor(vmax, 16, 64));
    vmax = fmaxf(vmax, __shfl_xor(vmax, 32, 64));
    if (quad == 0) pmax[wv * 256 + ct * 16 + n] = vmax;
  }
  __syncthreads();

  // ---- final cross-wave max + outputs ----
  {
    float v = fmaxf(fmaxf(pmax[tid], pmax[256 + tid]),
                    fmaxf(pmax[512 + tid], pmax[768 + tid]));
    out_x[(size_t)c * 256 + tid] = v;
  }
  if (tid < 3) out_pos[c * 3 + tid] = pos[qb + tid];
  if (tid == 0) out_batch[c] = (float)b;   // overwrite sel stash
}

extern "C" void kernel_launch(void* const* d_in, const int* in_sizes, int n_in,
                              void* d_out, int out_size, void* d_ws, size_t ws_size,
                              hipStream_t stream) {
  const float* x   = (const float*)d_in[0];
  const float* pos = (const float*)d_in[1];
  // d_in[2] = batch (int32), unused (layout known)
  const float* W1 = (const float*)d_in[3];
  const float* b1 = (const float*)d_in[4];
  const float* W2 = (const float*)d_in[5];
  const float* b2 = (const float*)d_in[6];
  const float* W3 = (const float*)d_in[7];
  const float* b3 = (const float*)d_in[8];

  float* out = (float*)d_out;
  float* out_pos   = out + (size_t)NCENT * 256;
  float* out_batch = out_pos + (size_t)NCENT * 3;
  f16* ws = (f16*)d_ws;   // 122880 B of f16 weights

  prep_kernel<<<WS_ELEMS / 256, 256, 0, stream>>>(W1, W2, W3, ws);
  fps_kernel<<<NCLOUD, 256, 0, stream>>>(pos, out_batch);
  conv_kernel<<<NCENT, 256, 0, stream>>>(x, pos, b1, b2, b3, ws,
                                         out_batch, out, out_pos, out_batch);
}

// Round 9
// 805.680 us; speedup vs baseline: 3.5067x; 1.2190x over previous
//
#include <hip/hip_runtime.h>

typedef unsigned int UI;
typedef unsigned long long ULL;
typedef _Float16 f16;
typedef _Float16 h8 __attribute__((ext_vector_type(8)));
typedef float f32x4 __attribute__((ext_vector_type(4)));

#define NB_PTS 4096
#define MB_SEL 1024
#define KNBR   64
#define NCLOUD 4
#define NCENT  (NCLOUD * MB_SEL)

// ws layout (f16): Wt1[128][96] @0 ; Wt2[128][128] @12288 ; Wt3[256][128] @28672
#define WT2_OFF 12288
#define WT3_OFF 28672
#define WS_ELEMS 61440

// exact np-order squared distance, f32
__device__ __forceinline__ float d2_np32(float dx, float dy, float dz) {
  return __fadd_rn(__fadd_rn(__fmul_rn(dx, dx), __fmul_rn(dy, dy)),
                   __fmul_rn(dz, dz));
}
// exact np-order squared distance, f64 (radius predicate — proven)
__device__ __forceinline__ double d2_np64(double dx, double dy, double dz) {
  return __dadd_rn(__dadd_rn(__dmul_rn(dx, dx), __dmul_rn(dy, dy)),
                   __dmul_rn(dz, dz));
}

// one u64-max DPP step: fetch neighbor's key halves, keep larger key.
// bound_ctrl=1 -> invalid source lanes read 0 (never wins: real keys > 0).
template <int CTRL>
__device__ __forceinline__ ULL dpp_max_step(ULL cur) {
  UI lo = (UI)cur, hi = (UI)(cur >> 32);
  UI nl = (UI)__builtin_amdgcn_update_dpp(0, (int)lo, CTRL, 0xf, 0xf, true);
  UI nh = (UI)__builtin_amdgcn_update_dpp(0, (int)hi, CTRL, 0xf, 0xf, true);
  ULL nv = ((ULL)nh << 32) | (ULL)nl;
  return nv > cur ? nv : cur;
}

// ---------------------------------------------------------------------------
// Kernel 0: weight prep — f32 -> f16, transposed to [n][k], K of W1 padded to 96
// ---------------------------------------------------------------------------
__global__ __launch_bounds__(256) void prep_kernel(const float* __restrict__ W1,
                                                   const float* __restrict__ W2,
                                                   const float* __restrict__ W3,
                                                   f16* __restrict__ ws) {
  int t = blockIdx.x * 256 + threadIdx.x;
  if (t < WT2_OFF) {                       // Wt1[n][k] : 128 x 96
    int n = t / 96, k = t - n * 96;
    ws[t] = (k < 67) ? (f16)W1[k * 128 + n] : (f16)0.f;
  } else if (t < WT3_OFF) {                // Wt2[n][k] : 128 x 128
    int u = t - WT2_OFF;
    int n = u >> 7, k = u & 127;
    ws[t] = (f16)W2[k * 128 + n];
  } else {                                 // Wt3[n][k] : 256 x 128
    int u = t - WT3_OFF;
    int n = u >> 7, k = u & 127;
    ws[t] = (f16)W3[k * 256 + n];
  }
}

// ---------------------------------------------------------------------------
// Kernel 1: FPS, exact np-float32 replication. 256 thr x 16 pts.
// Wave reduce via DPP (u64 key = d_bits<<32 | ~idx), one atomicMax per wave
// (4-way only), 3-phase slot rotation, ONE barrier per iteration.
// ---------------------------------------------------------------------------
__global__ __launch_bounds__(256) void fps_kernel(const float* __restrict__ pos,
                                                  float* __restrict__ selstash) {
  __shared__ float px[NB_PTS], py[NB_PTS], pz[NB_PTS];
  __shared__ ULL slots[3];
  const int b    = blockIdx.x;
  const int tid  = threadIdx.x;
  const int lane = tid & 63;

  float mx[16], my[16], mz[16], dist[16];
#pragma unroll
  for (int q = 0; q < 16; ++q) {
    int j = tid + q * 256;
    size_t base = ((size_t)b * NB_PTS + j) * 3;
    float X = pos[base], Y = pos[base + 1], Z = pos[base + 2];
    px[j] = X; py[j] = Y; pz[j] = Z;
    mx[q] = X; my[q] = Y; mz[q] = Z;
    dist[q] = __builtin_inff();
  }
  if (tid < 3) slots[tid] = 0ull;
  if (tid == 0) selstash[b * MB_SEL] = 0.0f;
  __syncthreads();

  float lx = px[0], ly = py[0], lz = pz[0];
  for (int k = 1; k < MB_SEL; ++k) {
    float bestv = -__builtin_inff();
    int   besti = 0x7fffffff;
#pragma unroll
    for (int q = 0; q < 16; ++q) {
      float d2 = d2_np32(mx[q] - lx, my[q] - ly, mz[q] - lz);
      float d  = fminf(dist[q], d2);     // np.minimum, f32
      dist[q] = d;
      bool gt = d > bestv;               // strict > keeps lowest q on tie
      bestv = gt ? d : bestv;
      besti = gt ? (tid + q * 256) : besti;
    }
    // key: larger d wins; on tie, smaller idx wins (np.argmax first-max)
    ULL key = ((ULL)__float_as_uint(bestv) << 32) | (ULL)(~(UI)besti);
    key = dpp_max_step<0x111>(key);   // row_shr:1
    key = dpp_max_step<0x112>(key);   // row_shr:2
    key = dpp_max_step<0x114>(key);   // row_shr:4
    key = dpp_max_step<0x118>(key);   // row_shr:8
    key = dpp_max_step<0x142>(key);   // row_bcast:15
    key = dpp_max_step<0x143>(key);   // row_bcast:31  -> lane 63 has wave max
    const int buf = k % 3;
    if (lane == 63) atomicMax(&slots[buf], key);
    if (tid == 0) slots[(k + 1) % 3] = 0ull;   // reset future slot (race-free)
    __syncthreads();
    ULL mk = slots[buf];
    int winner = (int)(~(UI)mk);
    if (tid == 0) selstash[b * MB_SEL + k] = (float)winner;
    lx = px[winner]; ly = py[winner]; lz = pz[winner];
  }
}

// ---------------------------------------------------------------------------
// Kernel 2: fused radius (f64) + MFMA-f16 MLP + masked max.
// One 256-thr block per centroid. Waves own disjoint OUTPUT column slices with
// all B-fragments register-resident (loaded once per block); all 64 rows
// shared through LDS. MFMA layouts verified (learn_hip m89/m91/m97).
// ---------------------------------------------------------------------------
__global__ __launch_bounds__(256, 2) void conv_kernel(
    const float* __restrict__ x, const float* __restrict__ pos,
    const float* __restrict__ b1, const float* __restrict__ b2,
    const float* __restrict__ b3, const f16* __restrict__ ws,
    const float* __restrict__ selstash, float* __restrict__ out_x,
    float* __restrict__ out_pos, float* __restrict__ out_batch) {
  __shared__ f16 featA[64 * 104];   // [row][k<96], stride 104
  __shared__ f16 h1s[64 * 136];     // [row][k<128], stride 136
  __shared__ f16 h2s[64 * 136];
  __shared__ float pmax[256];
  __shared__ ULL masks[64];
  __shared__ int nbrS[KNBR];
  __shared__ int nvS;

  const int tid  = threadIdx.x;
  const int lane = tid & 63;
  const int wv   = tid >> 6;
  const int c    = blockIdx.x;
  const int b    = c >> 10;
  const int s    = ((int)selstash[c]) & (NB_PTS - 1);
  const size_t qb = ((size_t)(b * NB_PTS + s)) * 3;
  const float qxf = pos[qb], qyf = pos[qb + 1], qzf = pos[qb + 2];
  const double qx = (double)qxf, qy = (double)qyf, qz = (double)qzf;
  const double RR = 0.2 * 0.2;

  // ---- radius: in-ball bitmask over all 4096 points ----
  for (int it = 0; it < 16; ++it) {
    const int ch = wv * 16 + it;
    const int j  = ch * 64 + lane;
    const size_t pb = ((size_t)b * NB_PTS + j) * 3;
    double d2 = d2_np64((double)pos[pb] - qx, (double)pos[pb + 1] - qy,
                        (double)pos[pb + 2] - qz);
    ULL m = __ballot(d2 <= RR);
    if (lane == 0) masks[ch] = m;
  }
  __syncthreads();

  // ---- B-fragment register loads (all waves; overlaps wave-0 extraction) ----
  const int n    = lane & 15;
  const int quad = lane >> 4;
  h8 B1[2][3], B2[2][4], B3[4][4];
  float bv1[2], bv2[2], bv3[4];
#pragma unroll
  for (int ct = 0; ct < 2; ++ct) {
    const int col = (2 * wv + ct) * 16 + n;
    bv1[ct] = b1[col];
    bv2[ct] = b2[col];
#pragma unroll
    for (int kt = 0; kt < 3; ++kt)
      B1[ct][kt] = *(const h8*)(ws + col * 96 + kt * 32 + quad * 8);
#pragma unroll
    for (int kt = 0; kt < 4; ++kt)
      B2[ct][kt] = *(const h8*)(ws + WT2_OFF + col * 128 + kt * 32 + quad * 8);
  }
#pragma unroll
  for (int ct = 0; ct < 4; ++ct) {
    const int col = (4 * wv + ct) * 16 + n;
    bv3[ct] = b3[col];
#pragma unroll
    for (int kt = 0; kt < 4; ++kt)
      B3[ct][kt] = *(const h8*)(ws + WT3_OFF + col * 128 + kt * 32 + quad * 8);
  }

  // ---- wave 0: first-64 in-ball extraction (ascending index) ----
  if (tid < 64) {
    ULL m = masks[tid];
    int pc = __popcll(m);
    int incl = pc;
#pragma unroll
    for (int off = 1; off < 64; off <<= 1) {
      int o = __shfl_up(incl, off, 64);
      if (tid >= off) incl += o;
    }
    int base = incl - pc;
    int tot  = __shfl(incl, 63, 64);
    int nvw  = min(tot, KNBR);
    if (tid == 63) nvS = nvw;
    int slot = base;
    ULL mm = m;
    while (mm && slot < KNBR) {
      int bit = __ffsll(mm) - 1;
      nbrS[slot++] = tid * 64 + bit;
      mm &= mm - 1;
    }
    if (tid >= nvw) nbrS[tid] = s;
  }
  __syncthreads();
  const int nv = nvS;

  // ---- gather: feat=[x_j, pos_j-pos_i, 0-pad] as f16, rows 0..63 ----
  {
    const int r = tid >> 2;           // row
    const int part = tid & 3;         // 16 x-feats each
    const int g = nbrS[r];
    const float* xrow = x + (((size_t)(b * NB_PTS + g)) << 6) + part * 16;
    float4 u0 = *(const float4*)(xrow);
    float4 u1 = *(const float4*)(xrow + 4);
    float4 u2 = *(const float4*)(xrow + 8);
    float4 u3 = *(const float4*)(xrow + 12);
    h8 o0, o1;
    o0[0]=(f16)u0.x; o0[1]=(f16)u0.y; o0[2]=(f16)u0.z; o0[3]=(f16)u0.w;
    o0[4]=(f16)u1.x; o0[5]=(f16)u1.y; o0[6]=(f16)u1.z; o0[7]=(f16)u1.w;
    o1[0]=(f16)u2.x; o1[1]=(f16)u2.y; o1[2]=(f16)u2.z; o1[3]=(f16)u2.w;
    o1[4]=(f16)u3.x; o1[5]=(f16)u3.y; o1[6]=(f16)u3.z; o1[7]=(f16)u3.w;
    *(h8*)(featA + r * 104 + part * 16)     = o0;
    *(h8*)(featA + r * 104 + part * 16 + 8) = o1;
    if (part == 3) {
      size_t gb = ((size_t)(b * NB_PTS + g)) * 3;
      h8 rv = {(f16)0.f,(f16)0.f,(f16)0.f,(f16)0.f,(f16)0.f,(f16)0.f,(f16)0.f,(f16)0.f};
      rv[0] = (f16)(pos[gb]     - qxf);
      rv[1] = (f16)(pos[gb + 1] - qyf);
      rv[2] = (f16)(pos[gb + 2] - qzf);
      h8 z = {(f16)0.f,(f16)0.f,(f16)0.f,(f16)0.f,(f16)0.f,(f16)0.f,(f16)0.f,(f16)0.f};
      *(h8*)(featA + r * 104 + 64) = rv;
      *(h8*)(featA + r * 104 + 72) = z;
      *(h8*)(featA + r * 104 + 80) = z;
      *(h8*)(featA + r * 104 + 88) = z;
    }
  }
  __syncthreads();

  // ---- L1: 67(->96) -> 128 ; wave w owns cols [32w,32w+32) ----
#pragma unroll
  for (int at = 0; at < 4; ++at) {
#pragma unroll
    for (int ct = 0; ct < 2; ++ct) {
      f32x4 acc = {0.f, 0.f, 0.f, 0.f};
#pragma unroll
      for (int kt = 0; kt < 3; ++kt) {
        h8 a = *(const h8*)(featA + (at * 16 + n) * 104 + kt * 32 + quad * 8);
        acc = __builtin_amdgcn_mfma_f32_16x16x32_f16(a, B1[ct][kt], acc, 0, 0, 0);
      }
      const int col = (2 * wv + ct) * 16 + n;
#pragma unroll
      for (int r = 0; r < 4; ++r)
        h1s[(at * 16 + quad * 4 + r) * 136 + col] = (f16)fmaxf(acc[r] + bv1[ct], 0.f);
    }
  }
  __syncthreads();

  // ---- L2: 128 -> 128 ----
#pragma unroll
  for (int at = 0; at < 4; ++at) {
#pragma unroll
    for (int ct = 0; ct < 2; ++ct) {
      f32x4 acc = {0.f, 0.f, 0.f, 0.f};
#pragma unroll
      for (int kt = 0; kt < 4; ++kt) {
        h8 a = *(const h8*)(h1s + (at * 16 + n) * 136 + kt * 32 + quad * 8);
        acc = __builtin_amdgcn_mfma_f32_16x16x32_f16(a, B2[ct][kt], acc, 0, 0, 0);
      }
      const int col = (2 * wv + ct) * 16 + n;
#pragma unroll
      for (int r = 0; r < 4; ++r)
        h2s[(at * 16 + quad * 4 + r) * 136 + col] = (f16)fmaxf(acc[r] + bv2[ct], 0.f);
    }
  }
  __syncthreads();

  // ---- L3: 128 -> 256, fused bias+relu+validity+row-max; cols [64w,64w+64) ----
  float vm[4] = {0.f, 0.f, 0.f, 0.f};   // valid max >= 0 (relu, nv>=1)
#pragma unroll
  for (int at = 0; at < 4; ++at) {
#pragma unroll
    for (int ct = 0; ct < 4; ++ct) {
      f32x4 acc = {0.f, 0.f, 0.f, 0.f};
#pragma unroll
      for (int kt = 0; kt < 4; ++kt) {
        h8 a = *(const h8*)(h2s + (at * 16 + n) * 136 + kt * 32 + quad * 8);
        acc = __builtin_amdgcn_mfma_f32_16x16x32_f16(a, B3[ct][kt], acc, 0, 0, 0);
      }
#pragma unroll
      for (int r = 0; r < 4; ++r) {
        float h = fmaxf(acc[r] + bv3[ct], 0.f);
        const int row = at * 16 + quad * 4 + r;
        vm[ct] = fmaxf(vm[ct], row < nv ? h : 0.f);
      }
    }
  }
#pragma unroll
  for (int ct = 0; ct < 4; ++ct) {
    vm[ct] = fmaxf(vm[ct], __shfl_xor(vm[ct], 16, 64));
    vm[ct] = fmaxf(vm[ct], __shfl_xor(vm[ct], 32, 64));
  }
  if (quad == 0) {
#pragma unroll
    for (int ct = 0; ct < 4; ++ct) pmax[wv * 64 + ct * 16 + n] = vm[ct];
  }
  __syncthreads();

  out_x[(size_t)c * 256 + tid] = pmax[tid];
  if (tid < 3) out_pos[c * 3 + tid] = pos[qb + tid];
  if (tid == 0) out_batch[c] = (float)b;   // overwrite sel stash
}

extern "C" void kernel_launch(void* const* d_in, const int* in_sizes, int n_in,
                              void* d_out, int out_size, void* d_ws, size_t ws_size,
                              hipStream_t stream) {
  const float* x   = (const float*)d_in[0];
  const float* pos = (const float*)d_in[1];
  // d_in[2] = batch (int32), unused (layout known)
  const float* W1 = (const float*)d_in[3];
  const float* b1 = (const float*)d_in[4];
  const float* W2 = (const float*)d_in[5];
  const float* b2 = (const float*)d_in[6];
  const float* W3 = (const float*)d_in[7];
  const float* b3 = (const float*)d_in[8];

  float* out = (float*)d_out;
  float* out_pos   = out + (size_t)NCENT * 256;
  float* out_batch = out_pos + (size_t)NCENT * 3;
  f16* ws = (f16*)d_ws;   // 122880 B of f16 weights

  prep_kernel<<<WS_ELEMS / 256, 256, 0, stream>>>(W1, W2, W3, ws);
  fps_kernel<<<NCLOUD, 256, 0, stream>>>(pos, out_batch);
  conv_kernel<<<NCENT, 256, 0, stream>>>(x, pos, b1, b2, b3, ws,
                                         out_batch, out, out_pos, out_batch);
}

// Round 10
// 799.604 us; speedup vs baseline: 3.5333x; 1.0076x over previous
//
#include <hip/hip_runtime.h>

typedef unsigned int UI;
typedef unsigned long long ULL;
typedef _Float16 f16;
typedef _Float16 h8 __attribute__((ext_vector_type(8)));
typedef float f32x4 __attribute__((ext_vector_type(4)));
typedef float fl2 __attribute__((ext_vector_type(2)));

#define NB_PTS 4096
#define MB_SEL 1024
#define KNBR   64
#define NCLOUD 4
#define NCENT  (NCLOUD * MB_SEL)

// ws layout (f16): Wt1[128][96] @0 ; Wt2[128][128] @12288 ; Wt3[256][128] @28672
#define WT2_OFF 12288
#define WT3_OFF 28672
#define WS_ELEMS 61440
#define PREP_BLOCKS 120   // 61440 / 512

// exact np-order squared distance, f64 (radius predicate — proven)
__device__ __forceinline__ double d2_np64(double dx, double dy, double dz) {
  return __dadd_rn(__dadd_rn(__dmul_rn(dx, dx), __dmul_rn(dy, dy)),
                   __dmul_rn(dz, dz));
}

// one u64-max DPP step (verified rounds 8/9)
template <int CTRL>
__device__ __forceinline__ ULL dpp_max_step(ULL cur) {
  UI lo = (UI)cur, hi = (UI)(cur >> 32);
  UI nl = (UI)__builtin_amdgcn_update_dpp(0, (int)lo, CTRL, 0xf, 0xf, true);
  UI nh = (UI)__builtin_amdgcn_update_dpp(0, (int)hi, CTRL, 0xf, 0xf, true);
  ULL nv = ((ULL)nh << 32) | (ULL)nl;
  return nv > cur ? nv : cur;
}

// ---------------------------------------------------------------------------
// Kernel 1: blocks 0..3 = FPS (exact np-f32, packed-fp32 q-loop);
//           blocks 4..123 = weight prep (f32 -> f16 transposed [n][k]).
// FPS: 512 thr x 8 pts (pairs in fl2). Per-wave DPP u64-key reduce, plain
// double-buffered slot writes (no atomics), ONE barrier per iteration.
// ---------------------------------------------------------------------------
__global__ __launch_bounds__(512) void fps_prep_kernel(
    const float* __restrict__ pos, float* __restrict__ selstash,
    const float* __restrict__ W1, const float* __restrict__ W2,
    const float* __restrict__ W3, f16* __restrict__ ws) {
#pragma clang fp contract(off)
  __shared__ float4 pp[NB_PTS];     // 64 KB: (x,y,z,pad)
  __shared__ ULL slots[2][8];

  if (blockIdx.x >= NCLOUD) {       // ---- prep path ----
    int t = (int)(blockIdx.x - NCLOUD) * 512 + threadIdx.x;
    if (t < WT2_OFF) {                       // Wt1[n][k] : 128 x 96
      int n = t / 96, k = t - n * 96;
      ws[t] = (k < 67) ? (f16)W1[k * 128 + n] : (f16)0.f;
    } else if (t < WT3_OFF) {                // Wt2[n][k] : 128 x 128
      int u = t - WT2_OFF;
      int n = u >> 7, k = u & 127;
      ws[t] = (f16)W2[k * 128 + n];
    } else if (t < WS_ELEMS) {               // Wt3[n][k] : 256 x 128
      int u = t - WT3_OFF;
      int n = u >> 7, k = u & 127;
      ws[t] = (f16)W3[k * 256 + n];
    }
    return;
  }

  const int b    = blockIdx.x;
  const int tid  = threadIdx.x;
  const int lane = tid & 63;
  const int wv   = tid >> 6;

  fl2 mx[4], my[4], mz[4], dist[4];
#pragma unroll
  for (int t = 0; t < 4; ++t) {
    int j0 = tid + (2 * t) * 512;
    int j1 = tid + (2 * t + 1) * 512;
    size_t a0 = ((size_t)b * NB_PTS + j0) * 3;
    size_t a1 = ((size_t)b * NB_PTS + j1) * 3;
    float X0 = pos[a0], Y0 = pos[a0 + 1], Z0 = pos[a0 + 2];
    float X1 = pos[a1], Y1 = pos[a1 + 1], Z1 = pos[a1 + 2];
    pp[j0] = make_float4(X0, Y0, Z0, 0.f);
    pp[j1] = make_float4(X1, Y1, Z1, 0.f);
    mx[t] = fl2{X0, X1}; my[t] = fl2{Y0, Y1}; mz[t] = fl2{Z0, Z1};
    dist[t] = fl2{__builtin_inff(), __builtin_inff()};
  }
  if (tid == 0) selstash[b * MB_SEL] = 0.0f;
  __syncthreads();

  int cur = 0;
  for (int k = 1; k < MB_SEL; ++k) {
    float4 w = pp[cur];               // one b128 broadcast read
    float bestv = -__builtin_inff();
    int   besti = 0x7fffffff;
#pragma unroll
    for (int t = 0; t < 4; ++t) {
      fl2 dx = mx[t] - w.x;           // v_pk_add(neg): RN per comp == scalar
      fl2 dy = my[t] - w.y;
      fl2 dz = mz[t] - w.z;
      fl2 dd = (dx * dx + dy * dy) + dz * dz;   // np order, contract off
      fl2 dc = dist[t];
      float d0 = fminf(dc.x, dd.x);   // np.minimum
      float d1 = fminf(dc.y, dd.y);
      dist[t] = fl2{d0, d1};
      if (d0 > bestv) { bestv = d0; besti = tid + (2 * t) * 512; }
      if (d1 > bestv) { bestv = d1; besti = tid + (2 * t + 1) * 512; }
    }
    // key: larger d wins; on tie smaller idx (np.argmax first-max)
    ULL key = ((ULL)__float_as_uint(bestv) << 32) | (ULL)(~(UI)besti);
    key = dpp_max_step<0x111>(key);   // row_shr:1
    key = dpp_max_step<0x112>(key);   // row_shr:2
    key = dpp_max_step<0x114>(key);   // row_shr:4
    key = dpp_max_step<0x118>(key);   // row_shr:8
    key = dpp_max_step<0x142>(key);   // row_bcast:15
    key = dpp_max_step<0x143>(key);   // row_bcast:31 -> lane 63 has wave max
    const int buf = k & 1;            // double buffer: write k+2 can't race read k
    if (lane == 63) slots[buf][wv] = key;
    __syncthreads();
    const ULL* sp = slots[buf];
    ULL mk = sp[0];
#pragma unroll
    for (int i = 1; i < 8; ++i) { ULL s = sp[i]; if (s > mk) mk = s; }
    int winner = (int)(~(UI)mk);
    if (tid == 0) selstash[b * MB_SEL + k] = (float)winner;
    cur = winner;
  }
}

// ---------------------------------------------------------------------------
// Kernel 2: fused radius (f64) + MFMA-f16 MLP + masked max.
// One 256-thr block per centroid, 3 blocks/CU. Waves own disjoint output
// columns; B1/B2 register-resident, B3 streamed from L2 (saves 64 VGPRs).
// Math order identical to round 9 -> bitwise-same output.
// ---------------------------------------------------------------------------
__global__ __launch_bounds__(256, 3) void conv_kernel(
    const float* __restrict__ x, const float* __restrict__ pos,
    const float* __restrict__ b1, const float* __restrict__ b2,
    const float* __restrict__ b3, const f16* __restrict__ ws,
    const float* __restrict__ selstash, float* __restrict__ out_x,
    float* __restrict__ out_pos, float* __restrict__ out_batch) {
  __shared__ f16 featA[64 * 104];   // [row][k<96], stride 104
  __shared__ f16 h1s[64 * 136];     // [row][k<128], stride 136
  __shared__ f16 h2s[64 * 136];
  __shared__ float pmax[256];
  __shared__ ULL masks[64];
  __shared__ int nbrS[KNBR];
  __shared__ int nvS;

  const int tid  = threadIdx.x;
  const int lane = tid & 63;
  const int wv   = tid >> 6;
  const int c    = blockIdx.x;
  const int b    = c >> 10;
  const int s    = ((int)selstash[c]) & (NB_PTS - 1);
  const size_t qb = ((size_t)(b * NB_PTS + s)) * 3;
  const float qxf = pos[qb], qyf = pos[qb + 1], qzf = pos[qb + 2];
  const double qx = (double)qxf, qy = (double)qyf, qz = (double)qzf;
  const double RR = 0.2 * 0.2;

  // ---- radius: in-ball bitmask over all 4096 points ----
  for (int it = 0; it < 16; ++it) {
    const int ch = wv * 16 + it;
    const int j  = ch * 64 + lane;
    const size_t pb = ((size_t)b * NB_PTS + j) * 3;
    double d2 = d2_np64((double)pos[pb] - qx, (double)pos[pb + 1] - qy,
                        (double)pos[pb + 2] - qz);
    ULL m = __ballot(d2 <= RR);
    if (lane == 0) masks[ch] = m;
  }
  __syncthreads();

  // ---- B1/B2 register preload (overlaps wave-0 extraction) ----
  const int n    = lane & 15;
  const int quad = lane >> 4;
  h8 B1[2][3], B2[2][4];
  float bv1[2], bv2[2], bv3[4];
#pragma unroll
  for (int ct = 0; ct < 2; ++ct) {
    const int col = (2 * wv + ct) * 16 + n;
    bv1[ct] = b1[col];
    bv2[ct] = b2[col];
#pragma unroll
    for (int kt = 0; kt < 3; ++kt)
      B1[ct][kt] = *(const h8*)(ws + col * 96 + kt * 32 + quad * 8);
#pragma unroll
    for (int kt = 0; kt < 4; ++kt)
      B2[ct][kt] = *(const h8*)(ws + WT2_OFF + col * 128 + kt * 32 + quad * 8);
  }
#pragma unroll
  for (int ct = 0; ct < 4; ++ct) bv3[ct] = b3[(4 * wv + ct) * 16 + n];

  // ---- wave 0: first-64 in-ball extraction (ascending index) ----
  if (tid < 64) {
    ULL m = masks[tid];
    int pc = __popcll(m);
    int incl = pc;
#pragma unroll
    for (int off = 1; off < 64; off <<= 1) {
      int o = __shfl_up(incl, off, 64);
      if (tid >= off) incl += o;
    }
    int base = incl - pc;
    int tot  = __shfl(incl, 63, 64);
    int nvw  = min(tot, KNBR);
    if (tid == 63) nvS = nvw;
    int slot = base;
    ULL mm = m;
    while (mm && slot < KNBR) {
      int bit = __ffsll(mm) - 1;
      nbrS[slot++] = tid * 64 + bit;
      mm &= mm - 1;
    }
    if (tid >= nvw) nbrS[tid] = s;
  }
  __syncthreads();
  const int nv = nvS;

  // ---- gather: feat=[x_j, pos_j-pos_i, 0-pad] as f16, rows 0..63 ----
  {
    const int r = tid >> 2;           // row
    const int part = tid & 3;         // 16 x-feats each
    const int g = nbrS[r];
    const float* xrow = x + (((size_t)(b * NB_PTS + g)) << 6) + part * 16;
    float4 u0 = *(const float4*)(xrow);
    float4 u1 = *(const float4*)(xrow + 4);
    float4 u2 = *(const float4*)(xrow + 8);
    float4 u3 = *(const float4*)(xrow + 12);
    h8 o0, o1;
    o0[0]=(f16)u0.x; o0[1]=(f16)u0.y; o0[2]=(f16)u0.z; o0[3]=(f16)u0.w;
    o0[4]=(f16)u1.x; o0[5]=(f16)u1.y; o0[6]=(f16)u1.z; o0[7]=(f16)u1.w;
    o1[0]=(f16)u2.x; o1[1]=(f16)u2.y; o1[2]=(f16)u2.z; o1[3]=(f16)u2.w;
    o1[4]=(f16)u3.x; o1[5]=(f16)u3.y; o1[6]=(f16)u3.z; o1[7]=(f16)u3.w;
    *(h8*)(featA + r * 104 + part * 16)     = o0;
    *(h8*)(featA + r * 104 + part * 16 + 8) = o1;
    if (part == 3) {
      size_t gb = ((size_t)(b * NB_PTS + g)) * 3;
      h8 rv = {(f16)0.f,(f16)0.f,(f16)0.f,(f16)0.f,(f16)0.f,(f16)0.f,(f16)0.f,(f16)0.f};
      rv[0] = (f16)(pos[gb]     - qxf);
      rv[1] = (f16)(pos[gb + 1] - qyf);
      rv[2] = (f16)(pos[gb + 2] - qzf);
      h8 z = {(f16)0.f,(f16)0.f,(f16)0.f,(f16)0.f,(f16)0.f,(f16)0.f,(f16)0.f,(f16)0.f};
      *(h8*)(featA + r * 104 + 64) = rv;
      *(h8*)(featA + r * 104 + 72) = z;
      *(h8*)(featA + r * 104 + 80) = z;
      *(h8*)(featA + r * 104 + 88) = z;
    }
  }
  __syncthreads();

  // ---- L1: 67(->96) -> 128 ; wave w owns cols [32w,32w+32) ----
#pragma unroll
  for (int at = 0; at < 4; ++at) {
#pragma unroll
    for (int ct = 0; ct < 2; ++ct) {
      f32x4 acc = {0.f, 0.f, 0.f, 0.f};
#pragma unroll
      for (int kt = 0; kt < 3; ++kt) {
        h8 a = *(const h8*)(featA + (at * 16 + n) * 104 + kt * 32 + quad * 8);
        acc = __builtin_amdgcn_mfma_f32_16x16x32_f16(a, B1[ct][kt], acc, 0, 0, 0);
      }
      const int col = (2 * wv + ct) * 16 + n;
#pragma unroll
      for (int r = 0; r < 4; ++r)
        h1s[(at * 16 + quad * 4 + r) * 136 + col] = (f16)fmaxf(acc[r] + bv1[ct], 0.f);
    }
  }
  __syncthreads();

  // ---- L2: 128 -> 128 ----
#pragma unroll
  for (int at = 0; at < 4; ++at) {
#pragma unroll
    for (int ct = 0; ct < 2; ++ct) {
      f32x4 acc = {0.f, 0.f, 0.f, 0.f};
#pragma unroll
      for (int kt = 0; kt < 4; ++kt) {
        h8 a = *(const h8*)(h1s + (at * 16 + n) * 136 + kt * 32 + quad * 8);
        acc = __builtin_amdgcn_mfma_f32_16x16x32_f16(a, B2[ct][kt], acc, 0, 0, 0);
      }
      const int col = (2 * wv + ct) * 16 + n;
#pragma unroll
      for (int r = 0; r < 4; ++r)
        h2s[(at * 16 + quad * 4 + r) * 136 + col] = (f16)fmaxf(acc[r] + bv2[ct], 0.f);
    }
  }
  __syncthreads();

  // ---- L3: 128 -> 256, B3 streamed from L2; fused bias+relu+valid+max ----
  float vm[4] = {0.f, 0.f, 0.f, 0.f};   // valid max >= 0 (relu, nv>=1)
#pragma unroll
  for (int at = 0; at < 4; ++at) {
#pragma unroll
    for (int ct = 0; ct < 4; ++ct) {
      const int col = (4 * wv + ct) * 16 + n;
      f32x4 acc = {0.f, 0.f, 0.f, 0.f};
#pragma unroll
      for (int kt = 0; kt < 4; ++kt) {
        h8 a = *(const h8*)(h2s + (at * 16 + n) * 136 + kt * 32 + quad * 8);
        h8 wfr = *(const h8*)(ws + WT3_OFF + col * 128 + kt * 32 + quad * 8);
        acc = __builtin_amdgcn_mfma_f32_16x16x32_f16(a, wfr, acc, 0, 0, 0);
      }
#pragma unroll
      for (int r = 0; r < 4; ++r) {
        float h = fmaxf(acc[r] + bv3[ct], 0.f);
        const int row = at * 16 + quad * 4 + r;
        vm[ct] = fmaxf(vm[ct], row < nv ? h : 0.f);
      }
    }
  }
#pragma unroll
  for (int ct = 0; ct < 4; ++ct) {
    vm[ct] = fmaxf(vm[ct], __shfl_xor(vm[ct], 16, 64));
    vm[ct] = fmaxf(vm[ct], __shfl_xor(vm[ct], 32, 64));
  }
  if (quad == 0) {
#pragma unroll
    for (int ct = 0; ct < 4; ++ct) pmax[wv * 64 + ct * 16 + n] = vm[ct];
  }
  __syncthreads();

  out_x[(size_t)c * 256 + tid] = pmax[tid];
  if (tid < 3) out_pos[c * 3 + tid] = pos[qb + tid];
  if (tid == 0) out_batch[c] = (float)b;   // overwrite sel stash
}

extern "C" void kernel_launch(void* const* d_in, const int* in_sizes, int n_in,
                              void* d_out, int out_size, void* d_ws, size_t ws_size,
                              hipStream_t stream) {
  const float* x   = (const float*)d_in[0];
  const float* pos = (const float*)d_in[1];
  // d_in[2] = batch (int32), unused (layout known)
  const float* W1 = (const float*)d_in[3];
  const float* b1 = (const float*)d_in[4];
  const float* W2 = (const float*)d_in[5];
  const float* b2 = (const float*)d_in[6];
  const float* W3 = (const float*)d_in[7];
  const float* b3 = (const float*)d_in[8];

  float* out = (float*)d_out;
  float* out_pos   = out + (size_t)NCENT * 256;
  float* out_batch = out_pos + (size_t)NCENT * 3;
  f16* ws = (f16*)d_ws;   // 122880 B of f16 weights

  fps_prep_kernel<<<NCLOUD + PREP_BLOCKS, 512, 0, stream>>>(pos, out_batch,
                                                            W1, W2, W3, ws);
  conv_kernel<<<NCENT, 256, 0, stream>>>(x, pos, b1, b2, b3, ws,
                                         out_batch, out, out_pos, out_batch);
}